// Round 1
// baseline (38.102 us; speedup 1.0000x reference)
//
#include <hip/hip_runtime.h>
#include <math.h>

#define IMG   1024
#define WT    64
#define HT    128
#define HROWS (HT + 8)   // 136 h-rows (output rows + 2*4 halo)
#define HPAD  72         // row stride in floats: 72%32=8 -> bank shift per row; 72%4==0 -> float4 aligned

__global__ __launch_bounds__(256) void dilate9x9(const float* __restrict__ in,
                                                 float* __restrict__ out) {
    __shared__ float h[HROWS][HPAD];

    const int tx  = blockIdx.x * WT;
    const int ty  = blockIdx.y * HT;
    const int b   = blockIdx.z;
    const int tid = threadIdx.x;

    const float* img  = in  + (size_t)b * IMG * IMG;
    float*       oimg = out + (size_t)b * IMG * IMG;

    // ---- Phase 1: horizontal 1x9 max into LDS -------------------------------
    // Tasks: HROWS x 16 x-groups (each group = 4 consecutive output columns).
    for (int t = tid; t < HROWS * 16; t += 256) {
        const int rr = t >> 4;     // 0..135  -> input row ty + rr - 4
        const int xg = t & 15;     // 0..15   -> columns tx + 4*xg .. +3
        const int iy = ty + rr - 4;

        float4 res;
        if (iy < 0 || iy >= IMG) {
            res = make_float4(-INFINITY, -INFINITY, -INFINITY, -INFINITY);
        } else {
            const int ix0 = tx + (xg << 2) - 4;   // first of 12 needed inputs
            float a[12];
            if (ix0 >= 0 && ix0 + 12 <= IMG) {
                // interior: 3 aligned float4 loads (ix0 is a multiple of 4)
                const float4* p = reinterpret_cast<const float4*>(img + (size_t)iy * IMG + ix0);
                float4 v0 = p[0], v1 = p[1], v2 = p[2];
                a[0]=v0.x; a[1]=v0.y; a[2]=v0.z;  a[3]=v0.w;
                a[4]=v1.x; a[5]=v1.y; a[6]=v1.z;  a[7]=v1.w;
                a[8]=v2.x; a[9]=v2.y; a[10]=v2.z; a[11]=v2.w;
            } else {
                // image edge in x: guarded scalar loads, -inf border (cv2 dilate)
                #pragma unroll
                for (int e = 0; e < 12; ++e) {
                    const int xi = ix0 + e;
                    a[e] = (xi >= 0 && xi < IMG) ? img[(size_t)iy * IMG + xi] : -INFINITY;
                }
            }
            // sliding max-9 over a[0..11] -> 4 results, shared-core trick (15 fmax)
            const float core = fmaxf(fmaxf(fmaxf(a[3], a[4]), fmaxf(a[5], a[6])),
                                     fmaxf(a[7], a[8]));              // max(a3..a8)
            const float p12  = fmaxf(a[1], a[2]);
            const float p012 = fmaxf(a[0], p12);
            const float q910 = fmaxf(a[9], a[10]);
            const float q911 = fmaxf(q910, a[11]);
            res.x = fmaxf(core, p012);                 // a0..a8
            res.y = fmaxf(core, fmaxf(p12, a[9]));     // a1..a9
            res.z = fmaxf(core, fmaxf(a[2], q910));    // a2..a10
            res.w = fmaxf(core, q911);                 // a3..a11
        }
        *reinterpret_cast<float4*>(&h[rr][xg << 2]) = res;
    }

    __syncthreads();

    // ---- Phase 2: vertical 9x1 max from LDS, store --------------------------
    // Tasks: HT rows x 16 x-groups = 2048 = exactly 8 per thread.
    for (int t = tid; t < HT * 16; t += 256) {
        const int r  = t >> 4;     // 0..127 output row within tile
        const int xg = t & 15;

        float4 m = *reinterpret_cast<const float4*>(&h[r][xg << 2]);
        #pragma unroll
        for (int dy = 1; dy < 9; ++dy) {
            const float4 v = *reinterpret_cast<const float4*>(&h[r + dy][xg << 2]);
            m.x = fmaxf(m.x, v.x);
            m.y = fmaxf(m.y, v.y);
            m.z = fmaxf(m.z, v.z);
            m.w = fmaxf(m.w, v.w);
        }
        *reinterpret_cast<float4*>(oimg + (size_t)(ty + r) * IMG + tx + (xg << 2)) = m;
    }
}

extern "C" void kernel_launch(void* const* d_in, const int* in_sizes, int n_in,
                              void* d_out, int out_size, void* d_ws, size_t ws_size,
                              hipStream_t stream) {
    const float* in  = (const float*)d_in[0];
    float*       out = (float*)d_out;
    const int B = in_sizes[0] / (IMG * IMG);   // 16
    dim3 grid(IMG / WT, IMG / HT, B);          // 16 x 8 x B
    dilate9x9<<<grid, 256, 0, stream>>>(in, out);
}

// Round 2
// 36.852 us; speedup vs baseline: 1.0339x; 1.0339x over previous
//
#include <hip/hip_runtime.h>
#include <math.h>

#define IMG   1024
#define WT    64
#define HT    128
#define HROWS (HT + 8)   // 136 h-rows (output rows + 2*4 halo)
#define HPAD  72         // row stride in floats: float4-aligned; conflicts measured negligible

__device__ __forceinline__ float4 max4(const float4 a, const float4 b) {
    return make_float4(fmaxf(a.x, b.x), fmaxf(a.y, b.y),
                       fmaxf(a.z, b.z), fmaxf(a.w, b.w));
}

__global__ __launch_bounds__(256) void dilate9x9(const float* __restrict__ in,
                                                 float* __restrict__ out) {
    __shared__ float h[HROWS][HPAD];

    const int tx  = blockIdx.x * WT;
    const int ty  = blockIdx.y * HT;
    const int b   = blockIdx.z;
    const int tid = threadIdx.x;

    const float* img  = in  + (size_t)b * IMG * IMG;
    float*       oimg = out + (size_t)b * IMG * IMG;

    // ---- Phase 1: horizontal 1x9 max into LDS -------------------------------
    // Tasks: HROWS x 16 x-groups (each group = 4 consecutive output columns).
    for (int t = tid; t < HROWS * 16; t += 256) {
        const int rr = t >> 4;     // 0..135  -> input row ty + rr - 4
        const int xg = t & 15;     // 0..15   -> columns tx + 4*xg .. +3
        const int iy = ty + rr - 4;

        float4 res;
        if (iy < 0 || iy >= IMG) {
            res = make_float4(-INFINITY, -INFINITY, -INFINITY, -INFINITY);
        } else {
            const int ix0 = tx + (xg << 2) - 4;   // first of 12 needed inputs
            float a[12];
            if (ix0 >= 0 && ix0 + 12 <= IMG) {
                // interior: 3 aligned float4 loads (ix0 is a multiple of 4)
                const float4* p = reinterpret_cast<const float4*>(img + (size_t)iy * IMG + ix0);
                float4 v0 = p[0], v1 = p[1], v2 = p[2];
                a[0]=v0.x; a[1]=v0.y; a[2]=v0.z;  a[3]=v0.w;
                a[4]=v1.x; a[5]=v1.y; a[6]=v1.z;  a[7]=v1.w;
                a[8]=v2.x; a[9]=v2.y; a[10]=v2.z; a[11]=v2.w;
            } else {
                // image edge in x: guarded scalar loads, -inf border (cv2 dilate)
                #pragma unroll
                for (int e = 0; e < 12; ++e) {
                    const int xi = ix0 + e;
                    a[e] = (xi >= 0 && xi < IMG) ? img[(size_t)iy * IMG + xi] : -INFINITY;
                }
            }
            // sliding max-9 over a[0..11] -> 4 results, shared-core trick (15 fmax)
            const float core = fmaxf(fmaxf(fmaxf(a[3], a[4]), fmaxf(a[5], a[6])),
                                     fmaxf(a[7], a[8]));              // max(a3..a8)
            const float p12  = fmaxf(a[1], a[2]);
            const float p012 = fmaxf(a[0], p12);
            const float q910 = fmaxf(a[9], a[10]);
            const float q911 = fmaxf(q910, a[11]);
            res.x = fmaxf(core, p012);                 // a0..a8
            res.y = fmaxf(core, fmaxf(p12, a[9]));     // a1..a9
            res.z = fmaxf(core, fmaxf(a[2], q910));    // a2..a10
            res.w = fmaxf(core, q911);                 // a3..a11
        }
        *reinterpret_cast<float4*>(&h[rr][xg << 2]) = res;
    }

    __syncthreads();

    // ---- Phase 2: vertical 9x1 max, van Herk style --------------------------
    // 256 tasks = 1/thread: 8 output rows x 4 cols. out[r] = max(h[r..r+8]).
    // 16 LDS row-reads for 8 outputs (2 reads/output vs 9 naive).
    {
        const int r0 = (tid >> 4) << 3;   // 0,8,...,120
        const int xc = (tid & 15) << 2;   // float column 0,4,...,60

        // suffix max over h[r0 .. r0+7]: S[t] = max(h[r0+t .. r0+7])
        float4 S[8];
        S[7] = *reinterpret_cast<const float4*>(&h[r0 + 7][xc]);
        #pragma unroll
        for (int j = 6; j >= 0; --j) {
            const float4 v = *reinterpret_cast<const float4*>(&h[r0 + j][xc]);
            S[j] = max4(v, S[j + 1]);
        }
        // running prefix max over h[r0+8 .. r0+15]; out[r0+t] = max(S[t], P_t)
        float4 P = *reinterpret_cast<const float4*>(&h[r0 + 8][xc]);
        float* orow = oimg + (size_t)(ty + r0) * IMG + tx + xc;
        #pragma unroll
        for (int t = 0; t < 8; ++t) {
            if (t > 0) {
                const float4 v = *reinterpret_cast<const float4*>(&h[r0 + 8 + t][xc]);
                P = max4(P, v);
            }
            *reinterpret_cast<float4*>(orow) = max4(S[t], P);
            orow += IMG;
        }
    }
}

extern "C" void kernel_launch(void* const* d_in, const int* in_sizes, int n_in,
                              void* d_out, int out_size, void* d_ws, size_t ws_size,
                              hipStream_t stream) {
    const float* in  = (const float*)d_in[0];
    float*       out = (float*)d_out;
    const int B = in_sizes[0] / (IMG * IMG);   // 16
    dim3 grid(IMG / WT, IMG / HT, B);          // 16 x 8 x B
    dilate9x9<<<grid, 256, 0, stream>>>(in, out);
}

// Round 3
// 35.304 us; speedup vs baseline: 1.0793x; 1.0439x over previous
//
#include <hip/hip_runtime.h>
#include <math.h>

#define IMG  1024
#define ROWS 32      // output rows per block; vertical halo amp = (ROWS+8)/ROWS = 1.25x

__device__ __forceinline__ float4 max4(const float4 a, const float4 b) {
    return make_float4(fmaxf(a.x, b.x), fmaxf(a.y, b.y),
                       fmaxf(a.z, b.z), fmaxf(a.w, b.w));
}

__global__ __launch_bounds__(256) void dilate9x9(const float* __restrict__ in,
                                                 float* __restrict__ out) {
    const int x0 = threadIdx.x << 2;          // 0..1020, thread's 4 output cols
    const int y0 = blockIdx.x * ROWS;         // output row range [y0, y0+ROWS)
    const int b  = blockIdx.y;

    const float* img  = in  + (size_t)b * IMG * IMG;
    float*       oimg = out + (size_t)b * IMG * IMG;

    const bool hasL = (x0 >= 4);              // left float4 in-bounds?
    const bool hasR = (x0 <= IMG - 8);        // right float4 in-bounds?

    // horizontal sliding max-9 for 4 outputs at row iy (cv2 border = -inf)
    auto load_hmax = [&](int iy) -> float4 {
        if (iy < 0 || iy >= IMG)
            return make_float4(-INFINITY, -INFINITY, -INFINITY, -INFINITY);
        const float4* p = reinterpret_cast<const float4*>(img + (size_t)iy * IMG + x0);
        const float4 v1 = p[0];
        const float4 v0 = hasL ? p[-1] : make_float4(-INFINITY, -INFINITY, -INFINITY, -INFINITY);
        const float4 v2 = hasR ? p[ 1] : make_float4(-INFINITY, -INFINITY, -INFINITY, -INFINITY);
        const float a0=v0.x,a1=v0.y,a2=v0.z,a3=v0.w;
        const float a4=v1.x,a5=v1.y,a6=v1.z,a7=v1.w;
        const float a8=v2.x,a9=v2.y,a10=v2.z,a11=v2.w;
        const float core = fmaxf(fmaxf(fmaxf(a3,a4),fmaxf(a5,a6)),fmaxf(a7,a8)); // a3..a8
        const float p12  = fmaxf(a1,a2);
        const float p012 = fmaxf(a0,p12);
        const float q910 = fmaxf(a9,a10);
        const float q911 = fmaxf(q910,a11);
        float4 r;
        r.x = fmaxf(core, p012);               // a0..a8
        r.y = fmaxf(core, fmaxf(p12,a9));      // a1..a9
        r.z = fmaxf(core, fmaxf(a2,q910));     // a2..a10
        r.w = fmaxf(core, q911);               // a3..a11
        return r;
    };

    // carried hmax rows: C[j] = hmax(row y0-4+j), j=0..7  (rows y0-4 .. y0+3)
    float4 C[8];
    #pragma unroll
    for (int j = 0; j < 8; ++j) C[j] = load_hmax(y0 - 4 + j);

    #pragma unroll
    for (int c = 0; c < ROWS / 8; ++c) {
        const int r0 = y0 + (c << 3);
        // suffix max over carried rows: S[t] = max(C[t..7]) = rows r0-4+t .. r0+3
        float4 S[8];
        S[7] = C[7];
        #pragma unroll
        for (int j = 6; j >= 0; --j) S[j] = max4(C[j], S[j + 1]);
        // running prefix over new rows r0+4 .. r0+11; out[r0+t] = max(S[t], P_t)
        float4 P;
        #pragma unroll
        for (int t = 0; t < 8; ++t) {
            const float4 H = load_hmax(r0 + 4 + t);
            P = (t == 0) ? H : max4(P, H);
            *reinterpret_cast<float4*>(oimg + (size_t)(r0 + t) * IMG + x0) = max4(S[t], P);
            C[t] = H;   // becomes next chunk's carry (rows r0+4 .. r0+11)
        }
    }
}

extern "C" void kernel_launch(void* const* d_in, const int* in_sizes, int n_in,
                              void* d_out, int out_size, void* d_ws, size_t ws_size,
                              hipStream_t stream) {
    const float* in  = (const float*)d_in[0];
    float*       out = (float*)d_out;
    const int B = in_sizes[0] / (IMG * IMG);   // 16
    dim3 grid(IMG / ROWS, B);                  // 32 x 16 = 512 blocks, 2/CU
    dilate9x9<<<grid, 256, 0, stream>>>(in, out);
}

// Round 4
// 31.250 us; speedup vs baseline: 1.2193x; 1.1297x over previous
//
#include <hip/hip_runtime.h>
#include <math.h>

#define IMG  1024
#define ROWS 16     // output rows per block -> 64 x 16 = 1024 blocks (4/CU)

#define NEG4 make_float4(-INFINITY, -INFINITY, -INFINITY, -INFINITY)

__device__ __forceinline__ float4 max4(const float4 a, const float4 b) {
    return make_float4(fmaxf(a.x, b.x), fmaxf(a.y, b.y),
                       fmaxf(a.z, b.z), fmaxf(a.w, b.w));
}

// sliding 9-wide max: 4 outputs from 12 inputs (v0=a0..3, v1=a4..7, v2=a8..11)
__device__ __forceinline__ float4 hmax9(const float4 v0, const float4 v1, const float4 v2) {
    const float core = fmaxf(fmaxf(fmaxf(v0.w, v1.x), fmaxf(v1.y, v1.z)),
                             fmaxf(v1.w, v2.x));                     // a3..a8
    const float p12  = fmaxf(v0.y, v0.z);
    const float q910 = fmaxf(v2.y, v2.z);
    float4 r;
    r.x = fmaxf(core, fmaxf(v0.x, p12));        // a0..a8
    r.y = fmaxf(core, fmaxf(p12, v2.y));        // a1..a9
    r.z = fmaxf(core, fmaxf(v0.z, q910));       // a2..a10
    r.w = fmaxf(core, fmaxf(q910, v2.w));       // a3..a11
    return r;
}

__global__ __launch_bounds__(256) void dilate9x9(const float* __restrict__ in,
                                                 float* __restrict__ out) {
    const int x0 = threadIdx.x << 2;          // thread's 4 output columns
    const int y0 = blockIdx.x * ROWS;
    const int b  = blockIdx.y;

    const float* img  = in  + (size_t)b * IMG * IMG;
    float*       oimg = out + (size_t)b * IMG * IMG;

    const bool hasL = (x0 >= 4);
    const bool hasR = (x0 <= IMG - 8);

    float4 C[8];   // carried hmax rows

    // ---- prologue: rows y0-4 .. y0+3 ---------------------------------------
    {
        float4 L0[8], L1[8], L2[8];
        bool   val[8];
        #pragma unroll
        for (int j = 0; j < 8; ++j) {         // 24 unconditional clustered loads
            const int iy = y0 - 4 + j;
            val[j] = (iy >= 0);               // iy < IMG always here (y0+3 <= 1011)
            const int cy = val[j] ? iy : 0;   // clamp; garbage fixed by select below
            const float4* p = reinterpret_cast<const float4*>(img + (size_t)cy * IMG + x0);
            L1[j] = p[0];
            L0[j] = *(hasL ? p - 1 : p);      // address-select keeps load unconditional
            L2[j] = *(hasR ? p + 1 : p);
        }
        #pragma unroll
        for (int j = 0; j < 8; ++j) {
            const float4 l0 = hasL ? L0[j] : NEG4;
            const float4 l2 = hasR ? L2[j] : NEG4;
            C[j] = val[j] ? hmax9(l0, L1[j], l2) : NEG4;
        }
    }

    // ---- main: 2 chunks of 8 output rows -----------------------------------
    #pragma unroll
    for (int c = 0; c < ROWS / 8; ++c) {
        const int r0 = y0 + (c << 3);

        float4 L0[8], L1[8], L2[8];
        bool   val[8];
        #pragma unroll
        for (int j = 0; j < 8; ++j) {         // 24 loads for rows r0+4 .. r0+11
            const int iy = r0 + 4 + j;
            val[j] = (iy < IMG);              // iy >= 0 always here
            const int cy = val[j] ? iy : IMG - 1;
            const float4* p = reinterpret_cast<const float4*>(img + (size_t)cy * IMG + x0);
            L1[j] = p[0];
            L0[j] = *(hasL ? p - 1 : p);
            L2[j] = *(hasR ? p + 1 : p);
        }

        // suffix max over carry (overlaps load latency; independent of loads)
        float4 S[8];
        S[7] = C[7];
        #pragma unroll
        for (int j = 6; j >= 0; --j) S[j] = max4(C[j], S[j + 1]);

        // consume: running prefix + store
        float4 P;
        #pragma unroll
        for (int t = 0; t < 8; ++t) {
            const float4 l0 = hasL ? L0[t] : NEG4;
            const float4 l2 = hasR ? L2[t] : NEG4;
            const float4 H  = val[t] ? hmax9(l0, L1[t], l2) : NEG4;
            P = (t == 0) ? H : max4(P, H);
            *reinterpret_cast<float4*>(oimg + (size_t)(r0 + t) * IMG + x0) = max4(S[t], P);
            C[t] = H;
        }
    }
}

extern "C" void kernel_launch(void* const* d_in, const int* in_sizes, int n_in,
                              void* d_out, int out_size, void* d_ws, size_t ws_size,
                              hipStream_t stream) {
    const float* in  = (const float*)d_in[0];
    float*       out = (float*)d_out;
    const int B = in_sizes[0] / (IMG * IMG);   // 16
    dim3 grid(IMG / ROWS, B);                  // 64 x 16 = 1024 blocks
    dilate9x9<<<grid, 256, 0, stream>>>(in, out);
}